// Round 9
// baseline (843.662 us; speedup 1.0000x reference)
//
#include <hip/hip_runtime.h>
#include <math.h>

#define N_NODES 50000
#define FEA 64
#define DEG 16
#define HID 256
#define NCLS 16
#define NP0 1351
#define NP0T 1408   // padded to 11*128
#define CTILES 11
#define NP1 37
#define EPSV 1e-5f

// ---------------- BatchNorm ----------------
__global__ __launch_bounds__(256) void bn_reduce(const float* __restrict__ x,
                                                 float* __restrict__ bnsum, float* __restrict__ bnsq) {
    __shared__ float s1[256], s2[256];
    int tid = threadIdx.x;
    int f = tid & 63, sub = tid >> 6;
    float a = 0.f, b = 0.f;
    for (int r = blockIdx.x * 4 + sub; r < N_NODES; r += gridDim.x * 4) {
        float v = x[r * FEA + f];
        a += v; b += v * v;
    }
    s1[tid] = a; s2[tid] = b;
    __syncthreads();
    if (tid < 64) {
        a = s1[tid] + s1[tid + 64] + s1[tid + 128] + s1[tid + 192];
        b = s2[tid] + s2[tid + 64] + s2[tid + 128] + s2[tid + 192];
        atomicAdd(&bnsum[tid], a);
        atomicAdd(&bnsq[tid], b);
    }
}

__global__ __launch_bounds__(256) void bn_apply(const float* __restrict__ x,
                                                const float* __restrict__ bnsum, const float* __restrict__ bnsq,
                                                const float* __restrict__ gamma, const float* __restrict__ beta,
                                                float* __restrict__ x0) {
    int gid = blockIdx.x * 256 + threadIdx.x;
    if (gid >= N_NODES * FEA) return;
    int f = gid & 63;
    float mu = bnsum[f] * (1.0f / N_NODES);
    float var = bnsq[f] * (1.0f / N_NODES) - mu * mu;
    float sc = gamma[f] / sqrtf(var + EPSV);
    x0[gid] = (x[gid] - mu) * sc + beta[f];
}

// ---------------- W0 transpose (64x256 -> 256x64) for coalesced G build ----------------
__global__ void transpose_W0(const float* __restrict__ W0, float* __restrict__ W0t) {
    int idx = blockIdx.x * 256 + threadIdx.x;
    if (idx < FEA * HID) {
        int f = idx >> 8, h = idx & 255;
        W0t[h * FEA + f] = W0[idx];
    }
}

// ---------------- Gt[k][j] = sum_m W0t[m][k]*C0[j][m]; c0n[j]=||C0_j||^2; pad j>=NP0 ----------------
__global__ __launch_bounds__(64) void compute_G2(const float* __restrict__ W0t, const float* __restrict__ C0,
                                                 float* __restrict__ Gt, float* __restrict__ c0n) {
    int j = blockIdx.x, k = threadIdx.x;           // 1408 blocks x 64 threads
    if (j >= NP0) {
        Gt[k * NP0T + j] = 0.f;
        if (k == 0) c0n[j] = 3.4e38f;
        return;
    }
    const float* c = C0 + j * HID;                 // wave-uniform reads
    float acc = 0.f;
    for (int m = 0; m < HID; ++m) acc += W0t[m * FEA + k] * c[m];   // coalesced over k
    Gt[k * NP0T + j] = acc;
    float cn = 0.f;
    for (int m = k; m < HID; m += 64) { float v = c[m]; cn += v * v; }
    for (int off = 32; off; off >>= 1) cn += __shfl_xor(cn, off);
    if (k == 0) c0n[j] = cn;
}

__global__ void cnorm(const float* __restrict__ C, float* __restrict__ cn) {
    int j = blockIdx.x, k = threadIdx.x;           // 37 blocks x 64 threads
    const float* c = C + j * HID;
    float acc = 0.f;
    for (int m = k; m < HID; m += 64) { float v = c[m]; acc += v * v; }
    for (int off = 32; off; off >>= 1) acc += __shfl_xor(acc, off);
    if (k == 0) cn[j] = acc;
}

// ---------------- level-0 argmin: 128x128 tile, 8x8/thread, 4 j-chunks, half-k B staging ----------------
// LDS = 35840(As) + 16896(Bs) + 512(cs) = 53248 < 64 KB  => 2 blocks/CU co-resident.
// dist = c0n[j] - 2*dot(x_i,G_j); chunk results merged via atomicMin on packed (ordered_dist<<32|j)
// (deterministic; low-bits j gives np.argmin first-min tie semantics). FMA order per acc is
// unchanged vs round-8 kernel => bit-identical distances.
__global__ __launch_bounds__(256, 2) void argmin0_split(const float* __restrict__ xcov,
                                                        const float* __restrict__ Gt,
                                                        const float* __restrict__ c0n,
                                                        unsigned long long* __restrict__ amin) {
    __shared__ float As[64 * 140];   // As[k][fr(r)], fr = r + 4*(r>>5)
    __shared__ float Bs[32 * 132];   // half-k tile: Bs[k2][j]
    __shared__ float cs[128];
    int t = threadIdx.x;
    int row0 = (blockIdx.x >> 2) * 128;
    int chunk = blockIdx.x & 3;
    int tile0 = chunk * 3;
    int tile1 = tile0 + 3; if (tile1 > CTILES) tile1 = CTILES;   // chunk 3: tiles 9,10

    // stage A: 2 threads per row, 32 k-entries each
    {
        int r = t & 127, half = t >> 7;
        int row = row0 + r;
        int fr = r + 4 * (r >> 5);
        if (row < N_NODES) {
            const float4* xp = (const float4*)(xcov + (size_t)row * FEA + half * 32);
            #pragma unroll
            for (int u = 0; u < 8; ++u) {
                float4 v = xp[u];
                int k = half * 32 + u * 4;
                As[(k+0)*140 + fr] = v.x; As[(k+1)*140 + fr] = v.y;
                As[(k+2)*140 + fr] = v.z; As[(k+3)*140 + fr] = v.w;
            }
        } else {
            #pragma unroll
            for (int u = 0; u < 8; ++u) {
                int k = half * 32 + u * 4;
                As[(k+0)*140+fr] = 0.f; As[(k+1)*140+fr] = 0.f;
                As[(k+2)*140+fr] = 0.f; As[(k+3)*140+fr] = 0.f;
            }
        }
    }

    int tr = t & 15, tc = t >> 4;
    int aoff = 8 * tr + 4 * (tr >> 2);   // f(8*tr)
    int boff = 8 * tc;
    int bkk = t >> 3, bpart = t & 7;     // B staging: 32 rows, 8 threads/row, 4 float4 each
    unsigned long long best[8];
    #pragma unroll
    for (int r = 0; r < 8; ++r) best[r] = ~0ull;

    for (int tile = tile0; tile < tile1; ++tile) {
        int j0 = tile * 128;
        float acc[8][8];
        #pragma unroll
        for (int r = 0; r < 8; ++r)
            #pragma unroll
            for (int c = 0; c < 8; ++c) acc[r][c] = 0.f;

        for (int kh = 0; kh < 2; ++kh) {
            __syncthreads();               // Bs/cs safe to overwrite (all waves past last k-loop/pack)
            {
                const float* gr = Gt + (size_t)(kh * 32 + bkk) * NP0T + j0;
                #pragma unroll
                for (int u = 0; u < 4; ++u) {
                    int gi = bpart + 8 * u;
                    float4 v = *(const float4*)(gr + gi * 4);
                    *(float4*)(Bs + bkk * 132 + gi * 4) = v;
                }
            }
            if (kh == 0 && t < 128) cs[t] = c0n[j0 + t];
            __syncthreads();
            #pragma unroll 4
            for (int k2 = 0; k2 < 32; ++k2) {
                int k = kh * 32 + k2;
                float4 av0 = *(const float4*)(As + k * 140 + aoff);
                float4 av1 = *(const float4*)(As + k * 140 + aoff + 4);
                float4 bv0 = *(const float4*)(Bs + k2 * 132 + boff);
                float4 bv1 = *(const float4*)(Bs + k2 * 132 + boff + 4);
                float av[8] = {av0.x, av0.y, av0.z, av0.w, av1.x, av1.y, av1.z, av1.w};
                float bv[8] = {bv0.x, bv0.y, bv0.z, bv0.w, bv1.x, bv1.y, bv1.z, bv1.w};
                #pragma unroll
                for (int r = 0; r < 8; ++r)
                    #pragma unroll
                    for (int c = 0; c < 8; ++c) acc[r][c] += av[r] * bv[c];
            }
        }
        #pragma unroll
        for (int c = 0; c < 8; ++c) {
            int j = j0 + boff + c;
            float cn = cs[boff + c];
            #pragma unroll
            for (int r = 0; r < 8; ++r) {
                float d = cn - 2.0f * acc[r][c];
                unsigned s = __float_as_uint(d);
                unsigned u2 = ((int)s < 0) ? ~s : (s | 0x80000000u);  // monotone float->uint
                unsigned long long p = ((unsigned long long)u2 << 32) | (unsigned)j;
                if (p < best[r]) best[r] = p;
            }
        }
    }

    __syncthreads();
    unsigned long long* pmin = (unsigned long long*)Bs;   // 128*16*8 = 16384 <= 16896, fits
    #pragma unroll
    for (int r = 0; r < 8; ++r) pmin[(8 * tr + r) * 16 + tc] = best[r];
    __syncthreads();
    if (t < 128) {
        unsigned long long b = pmin[t * 16];
        #pragma unroll
        for (int q = 1; q < 16; ++q) {
            unsigned long long v = pmin[t * 16 + q];
            if (v < b) b = v;
        }
        int row = row0 + t;
        if (row < N_NODES) atomicMin(&amin[row], b);
    }
}

// ---------------- a0 extraction + wave-aggregated histogram ----------------
__global__ __launch_bounds__(256) void hist0(const unsigned long long* __restrict__ amin,
                                             int* __restrict__ a0, int* __restrict__ hist) {
    int i = blockIdx.x * 256 + threadIdx.x;
    bool act = i < N_NODES;
    int j = act ? (int)(unsigned)amin[i] : -1;
    if (act) a0[i] = j;
    unsigned long long todo = __ballot(act);
    int lane = threadIdx.x & 63;
    while (todo) {
        int leader = __ffsll((long long)todo) - 1;
        int lj = __shfl(j, leader);
        unsigned long long grp = __ballot(act && j == lj);
        if (lane == leader) atomicAdd(&hist[lj], __popcll(grp));
        todo &= ~grp;
    }
}

__global__ __launch_bounds__(256) void scan0(const int* __restrict__ hist, int* __restrict__ off,
                                             int* __restrict__ cursor) {
    __shared__ int wsum[4];
    int t = threadIdx.x;
    int c0 = t * 6;                      // 256*6 = 1536 >= 1351
    int loc[6]; int s = 0;
    #pragma unroll
    for (int u = 0; u < 6; ++u) {
        int j = c0 + u;
        int h = (j < NP0) ? hist[j] : 0;
        loc[u] = s; s += h;
    }
    int lane = t & 63, w = t >> 6;
    int v = s;
    #pragma unroll
    for (int d = 1; d < 64; d <<= 1) {
        int up = __shfl_up(v, d);
        if (lane >= d) v += up;
    }
    if (lane == 63) wsum[w] = v;
    __syncthreads();
    int woff = 0;
    for (int q = 0; q < w; ++q) woff += wsum[q];
    int excl = woff + v - s;             // exclusive prefix of this thread's chunk
    #pragma unroll
    for (int u = 0; u < 6; ++u) {
        int j = c0 + u;
        if (j < NP0) { off[j] = excl + loc[u]; cursor[j] = excl + loc[u]; }
    }
    if (t == 255) off[NP0] = excl + s;   // total = N_NODES
}

__global__ __launch_bounds__(256) void scatter0(const int* __restrict__ a0, int* __restrict__ cursor,
                                                int* __restrict__ order, int* __restrict__ csrt) {
    int i = blockIdx.x * 256 + threadIdx.x;
    bool act = i < N_NODES;
    int j = act ? a0[i] : -1;
    int lane = threadIdx.x & 63;
    unsigned long long todo = __ballot(act);
    int pos = 0;
    while (todo) {
        int leader = __ffsll((long long)todo) - 1;
        int lj = __shfl(j, leader);
        unsigned long long grp = __ballot(act && j == lj);
        int base = 0;
        if (lane == leader) base = atomicAdd(&cursor[lj], __popcll(grp));
        base = __shfl(base, leader);
        if (act && j == lj)
            pos = base + __popcll(grp & ((1ull << lane) - 1ull));
        todo &= ~grp;
    }
    if (act) { order[pos] = i; csrt[pos] = j; }
}

// ---------------- skew-robust pooled sum, DOUBLE accumulation (replay-deterministic) ----------------
__global__ __launch_bounds__(256) void pool0seg(const int* __restrict__ order, const int* __restrict__ csrt,
                                                const float* __restrict__ xcov, double* __restrict__ p0d) {
    int lane = threadIdx.x & 63;
    int w = threadIdx.x >> 6;
    int base = (blockIdx.x * 4 + w) * 16;
    if (base >= N_NODES) return;
    int n = N_NODES - base; if (n > 16) n = 16;
    float vals[16]; int cl[16];
    #pragma unroll
    for (int r = 0; r < 16; ++r) {
        if (r < n) {
            int idx = order[base + r];        // wave-uniform -> broadcast
            cl[r] = csrt[base + r];
            vals[r] = xcov[(size_t)idx * FEA + lane];   // coalesced 256B row
        } else { cl[r] = -1; vals[r] = 0.f; }
    }
    double acc = (double)vals[0]; int cur = cl[0];
    #pragma unroll
    for (int r = 1; r < 16; ++r) {
        if (r < n) {
            if (cl[r] == cur) { acc += (double)vals[r]; }
            else { atomicAdd(&p0d[(size_t)cur * FEA + lane], acc); acc = (double)vals[r]; cur = cl[r]; }
        }
    }
    atomicAdd(&p0d[(size_t)cur * FEA + lane], acc);
}

__global__ void pool_fin0(const double* __restrict__ p0d, const int* __restrict__ hist,
                          float* __restrict__ p0, int total) {
    int gid = blockIdx.x * 256 + threadIdx.x;
    if (gid < total) p0[gid] = (float)(p0d[gid] / (double)max(hist[gid >> 6], 1));
}

// ---------------- level-1: h1 = p0 @ W1, argmin vs C1 (a1 only) ----------------
__global__ __launch_bounds__(64) void level1(const float* __restrict__ p0, const float* __restrict__ W1,
                                             const float* __restrict__ C1, const float* __restrict__ c1n,
                                             int* __restrict__ a1) {
    int i = blockIdx.x;          // 1351 blocks, one wave each
    int lane = threadIdx.x;
    const float* pr = p0 + (size_t)i * FEA;
    float h[4] = {0.f, 0.f, 0.f, 0.f};
    for (int k = 0; k < FEA; ++k) {
        float pv = pr[k];                         // wave-uniform
        #pragma unroll
        for (int q = 0; q < 4; ++q) h[q] += pv * W1[k * HID + q * 64 + lane];
    }
    float hh = h[0]*h[0] + h[1]*h[1] + h[2]*h[2] + h[3]*h[3];
    for (int off = 32; off; off >>= 1) hh += __shfl_xor(hh, off);
    float best = 3.4e38f; int bj = 0;
    for (int j = 0; j < NP1; ++j) {
        const float* cj = C1 + j * HID;
        float dp = h[0]*cj[lane] + h[1]*cj[64+lane] + h[2]*cj[128+lane] + h[3]*cj[192+lane];
        for (int off = 32; off; off >>= 1) dp += __shfl_xor(dp, off);
        float d = hh - 2.0f * dp + c1n[j];
        if (d < best) { best = d; bj = j; }
    }
    if (lane == 0) a1[i] = bj;
}

// ---------------- pool p0 -> p1: one block per cluster, atomic-free scan of a1 ----------------
__global__ __launch_bounds__(256) void pool1(const float* __restrict__ p0, const int* __restrict__ a1,
                                             float* __restrict__ p1) {
    __shared__ float s[4][64];
    __shared__ int scnt[4];
    int j = blockIdx.x;                    // 37 blocks
    int lane = threadIdx.x & 63, w = threadIdx.x >> 6;
    float acc = 0.f; int cnt = 0;
    for (int i = w; i < NP0; i += 4) {
        if (a1[i] == j) { acc += p0[i * FEA + lane]; cnt++; }
    }
    s[w][lane] = acc;
    if (lane == 0) scnt[w] = cnt;
    __syncthreads();
    if (w == 0) {
        float tsum = s[0][lane] + s[1][lane] + s[2][lane] + s[3][lane];
        int c = scnt[0] + scnt[1] + scnt[2] + scnt[3];
        p1[j * FEA + lane] = tsum / fmaxf((float)c, 1.0f);
    }
}

// ---------------- level-2 (N2=1 => a2==0): p2 = mean(p1), corr2, g1sq, loss part 2 ----------------
__global__ __launch_bounds__(256) void level2(const float* __restrict__ p1, const float* __restrict__ fc,
                                              float* __restrict__ corr2, float* __restrict__ g1sq,
                                              float* __restrict__ loss2f) {
    __shared__ float p2s[64];
    __shared__ float lacc[64];
    int tid = threadIdx.x;
    if (tid < 64) {
        float s = 0.f;
        for (int i = 0; i < NP1; ++i) s += p1[i * FEA + tid];
        p2s[tid] = s * (1.0f / NP1);
        lacc[tid] = 0.f;
    }
    __syncthreads();
    for (int t = tid; t < NP1 * FEA; t += 256) {
        int f = t & 63;
        float dv = p1[t] - p2s[f];
        float c2 = dv * dv;
        corr2[t] = c2;
        float sg = 2.0f / (1.0f + __expf(-(fc[f] - c2)));
        g1sq[t] = sg * sg;
        atomicAdd(&lacc[f], c2);
    }
    __syncthreads();
    if (tid < 64) loss2f[tid] = lacc[tid] * (1.0f / NP1);
}

// ---------------- corr1, g0sq, loss part 1 ----------------
__global__ __launch_bounds__(256) void corr1_g0(const float* __restrict__ p0, const float* __restrict__ p1,
                                                const int* __restrict__ a1, const float* __restrict__ corr2,
                                                float* __restrict__ g0sq, float* __restrict__ loss1g) {
    __shared__ float sh[256];
    int tid = threadIdx.x;
    int f = tid & 63, sub = tid >> 6;
    int i = blockIdx.x * 4 + sub;
    float c1v = 0.f;
    if (i < NP0) {
        int a = a1[i];
        float dv = p0[i * FEA + f] - p1[a * FEA + f];
        c1v = dv * dv;
        float sg = 2.0f / (1.0f + __expf(-(corr2[a * FEA + f] - c1v)));
        g0sq[i * FEA + f] = sg * sg;
    }
    sh[tid] = c1v;
    __syncthreads();
    if (tid < 64) atomicAdd(&loss1g[tid], sh[tid] + sh[tid+64] + sh[tid+128] + sh[tid+192]);
}

__global__ void loss_final(const float* __restrict__ loss1g, const float* __restrict__ loss2f,
                           float* __restrict__ out_loss) {
    int lane = threadIdx.x;
    float v = loss1g[lane] * (1.0f / NP0) + loss2f[lane];
    for (int off = 32; off; off >>= 1) v += __shfl_xor(v, off);
    if (lane == 0) out_loss[0] = v * (1.0f / FEA) * 0.5f;   // /(NPOOL-1)
}

__global__ void cl1map(const int* __restrict__ a0, const int* __restrict__ a1, int* __restrict__ cl1) {
    int i = blockIdx.x * 256 + threadIdx.x;
    if (i < N_NODES) cl1[i] = a1[a0[i]];
}

// ---------------- fused per-row softmax + propagation, one wave per row ----------------
__global__ __launch_bounds__(256) void prop(const float* __restrict__ xin, const float* __restrict__ x0,
                                            const int* __restrict__ cols, const float* __restrict__ avals,
                                            const int* __restrict__ cl0, const int* __restrict__ cl1,
                                            const float* __restrict__ g0sq, const float* __restrict__ g1sq,
                                            float* __restrict__ xout) {
    int lane = threadIdx.x & 63;
    int i = blockIdx.x * 4 + __builtin_amdgcn_readfirstlane(threadIdx.x >> 6);
    int s0 = cl0[i], s1 = cl1[i];
    float g0f = g0sq[s0 * FEA + lane];
    float g1f = g1sq[s1 * FEA + lane];
    float x0f = x0[(size_t)i * FEA + lane];
    int ce[DEG]; float v[DEG];
    float m = -3.4e38f;
    #pragma unroll
    for (int e = 0; e < DEG; ++e) {
        int c = cols[i * DEG + e];
        ce[e] = c;
        float val = avals[i * DEG + e];
        if (cl0[c] == s0) val += g0f;
        if (cl1[c] == s1) val += g1f;
        v[e] = val;
        m = fmaxf(m, val);
    }
    float se = 0.f, acc = 0.f;
    #pragma unroll
    for (int e = 0; e < DEG; ++e) {
        float w = __expf(v[e] - m);
        se += w;
        acc += w * xin[(size_t)ce[e] * FEA + lane];
    }
    xout[(size_t)i * FEA + lane] = acc / se + x0f;   // ALPHA = 1
}

// ---------------- fused GEMM + bias + PReLU: C[M x 128-tile] = A(chunked K) @ W + b ----------------
__global__ __launch_bounds__(256, 2) void gemm_prelu(const float* __restrict__ s0, const float* __restrict__ s1,
                                                     const float* __restrict__ s2, const float* __restrict__ s3,
                                                     int nchunks, int lda,
                                                     const float* __restrict__ W, const float* __restrict__ b,
                                                     const float* __restrict__ pp, float* __restrict__ out) {
    __shared__ float As[64 * 144];   // As[k][fr(r)], fr = r + 4*(r>>5)
    __shared__ float Bs[64 * 140];   // Bs[k][fc(n)], fc = n + 4*(n>>5)
    int t = threadIdx.x;
    int mt = blockIdx.x >> 1, nt = blockIdx.x & 1;
    int row0 = mt * 128, n0 = nt * 128;
    int tr = t & 15, tc = t >> 4;
    int aoff = 8 * tr + 4 * (tr >> 2);
    int boff = 8 * tc + 4 * (tc >> 2);

    float acc[8][8];
    #pragma unroll
    for (int r = 0; r < 8; ++r)
        #pragma unroll
        for (int c = 0; c < 8; ++c) acc[r][c] = 0.f;

    int ar = t & 127, ahalf = t >> 7;      // A staging: 2 threads/row, 32 k each
    int arow = row0 + ar;
    int afr = ar + 4 * (ar >> 5);
    int bkk = t >> 2, bpart = t & 3;       // B staging: thread per k-row quarter

    for (int c = 0; c < nchunks; ++c) {
        const float* Ap = (c == 0) ? s0 : (c == 1) ? s1 : (c == 2) ? s2 : s3;
        __syncthreads();
        // stage A chunk (transposed)
        if (arow < N_NODES) {
            const float4* xp = (const float4*)(Ap + (size_t)arow * lda + ahalf * 32);
            #pragma unroll
            for (int u = 0; u < 8; ++u) {
                float4 v = xp[u];
                int k = ahalf * 32 + u * 4;
                As[(k+0)*144 + afr] = v.x; As[(k+1)*144 + afr] = v.y;
                As[(k+2)*144 + afr] = v.z; As[(k+3)*144 + afr] = v.w;
            }
        } else {
            #pragma unroll
            for (int u = 0; u < 8; ++u) {
                int k = ahalf * 32 + u * 4;
                As[(k+0)*144+afr] = 0.f; As[(k+1)*144+afr] = 0.f;
                As[(k+2)*144+afr] = 0.f; As[(k+3)*144+afr] = 0.f;
            }
        }
        // stage B chunk: W rows c*64+kk, cols n0..n0+127
        {
            const float* wr = W + (size_t)(c * 64 + bkk) * HID + n0;
            #pragma unroll
            for (int u = 0; u < 8; ++u) {
                int ci = (bpart + 4 * u) * 4;            // 0..124 step 4
                float4 v = *(const float4*)(wr + ci);
                int fc = ci + 4 * (ci >> 5);
                *(float4*)(Bs + bkk * 140 + fc) = v;
            }
        }
        __syncthreads();
        for (int k = 0; k < 64; ++k) {
            float4 av0 = *(const float4*)(As + k * 144 + aoff);
            float4 av1 = *(const float4*)(As + k * 144 + aoff + 4);
            float4 bv0 = *(const float4*)(Bs + k * 140 + boff);
            float4 bv1 = *(const float4*)(Bs + k * 140 + boff + 4);
            float av[8] = {av0.x, av0.y, av0.z, av0.w, av1.x, av1.y, av1.z, av1.w};
            float bv[8] = {bv0.x, bv0.y, bv0.z, bv0.w, bv1.x, bv1.y, bv1.z, bv1.w};
            #pragma unroll
            for (int r = 0; r < 8; ++r)
                #pragma unroll
                for (int cc = 0; cc < 8; ++cc) acc[r][cc] += av[r] * bv[cc];
        }
    }
    // epilogue: bias + PReLU, cols n0+8*tc .. +7 (contiguous)
    float p = pp[0];
    float bb[8];
    #pragma unroll
    for (int cc = 0; cc < 8; ++cc) bb[cc] = b[n0 + 8 * tc + cc];
    #pragma unroll
    for (int r = 0; r < 8; ++r) {
        int row = row0 + 8 * tr + r;
        if (row >= N_NODES) break;
        float* o = out + (size_t)row * HID + n0 + 8 * tc;
        float4 o0, o1;
        float h;
        h = acc[r][0] + bb[0]; o0.x = h >= 0.f ? h : p * h;
        h = acc[r][1] + bb[1]; o0.y = h >= 0.f ? h : p * h;
        h = acc[r][2] + bb[2]; o0.z = h >= 0.f ? h : p * h;
        h = acc[r][3] + bb[3]; o0.w = h >= 0.f ? h : p * h;
        h = acc[r][4] + bb[4]; o1.x = h >= 0.f ? h : p * h;
        h = acc[r][5] + bb[5]; o1.y = h >= 0.f ? h : p * h;
        h = acc[r][6] + bb[6]; o1.z = h >= 0.f ? h : p * h;
        h = acc[r][7] + bb[7]; o1.w = h >= 0.f ? h : p * h;
        *(float4*)(o) = o0;
        *(float4*)(o + 4) = o1;
    }
}

// ---------------- MLP layer 3 + log_softmax; lane = (row_sub, class) ----------------
__global__ __launch_bounds__(256) void mlp3(const float* __restrict__ hin, const float* __restrict__ W3,
                                            const float* __restrict__ b3, float* __restrict__ out) {
    __shared__ float Ws[HID * NCLS];
    int tid = threadIdx.x;
    for (int t = tid; t < HID * NCLS; t += 256) Ws[t] = W3[t];
    __syncthreads();
    int lane = tid & 63;
    int wv = __builtin_amdgcn_readfirstlane(tid >> 6);
    int rs = lane >> 4, c = lane & 15;
    int row = blockIdx.x * 16 + wv * 4 + rs;    // 3125 blocks * 16 rows = 50000 exactly
    const float4* hr = (const float4*)(hin + (size_t)row * HID);
    float acc = b3[c];
    for (int k4 = 0; k4 < 64; ++k4) {
        float4 h = hr[k4];
        int k = k4 * 4;
        acc += h.x * Ws[k * NCLS + c];
        acc += h.y * Ws[(k + 1) * NCLS + c];
        acc += h.z * Ws[(k + 2) * NCLS + c];
        acc += h.w * Ws[(k + 3) * NCLS + c];
    }
    float m = acc;
    #pragma unroll
    for (int off = 1; off < 16; off <<= 1) m = fmaxf(m, __shfl_xor(m, off));
    float e = __expf(acc - m);
    float s = e;
    #pragma unroll
    for (int off = 1; off < 16; off <<= 1) s += __shfl_xor(s, off);
    out[(size_t)row * NCLS + c] = acc - m - __logf(s);
}

extern "C" void kernel_launch(void* const* d_in, const int* in_sizes, int n_in,
                              void* d_out, int out_size, void* d_ws, size_t ws_size,
                              hipStream_t stream) {
    const float* x     = (const float*)d_in[0];
    const float* xcov  = (const float*)d_in[1];
    const float* avals = (const float*)d_in[2];
    const float* fc    = (const float*)d_in[3];
    const float* gamma = (const float*)d_in[4];
    const float* beta  = (const float*)d_in[5];
    const float* W0    = (const float*)d_in[6];
    const float* C0    = (const float*)d_in[7];
    const float* W1    = (const float*)d_in[8];
    const float* C1    = (const float*)d_in[9];
    // d_in[10], d_in[11] (W2, C2) only affect a2, which is argmin over 1 cluster -> always 0. Unused.
    const float* mW1   = (const float*)d_in[12];
    const float* mb1   = (const float*)d_in[13];
    const float* mp1   = (const float*)d_in[14];
    const float* mW2   = (const float*)d_in[15];
    const float* mb2   = (const float*)d_in[16];
    const float* mp2   = (const float*)d_in[17];
    const float* mW3   = (const float*)d_in[18];
    const float* mb3   = (const float*)d_in[19];
    // d_in[20] adj_rows == repeat(arange(N), 16) -> row of edge e is e>>4. Unused.
    const int* cols    = (const int*)d_in[21];

    float* ws = (float*)d_ws;
    size_t off = 0;
    auto alloc = [&](size_t n) { float* p = ws + off; off += (n + 63) & ~(size_t)63; return p; };

    float* x0    = alloc((size_t)N_NODES * FEA);
    float* h1b   = alloc((size_t)N_NODES * HID);   // xb1 aliases its head
    float* h2b   = alloc((size_t)N_NODES * HID);   // xb2 aliases its head
    float* W0t   = alloc(HID * FEA);
    float* Gt    = alloc((size_t)FEA * NP0T);
    float* c0n   = alloc(NP0T);
    float* c1n   = alloc(NP1);
    float* g0sq  = alloc(NP0 * FEA);
    float* g1sq  = alloc(NP1 * FEA);
    float* corr2 = alloc(NP1 * FEA);
    float* loss2f= alloc(64);
    float* p1    = alloc(NP1 * FEA);
    float* p0    = alloc(NP0 * FEA);               // written by pool_fin0
    int*   a0    = (int*)alloc(N_NODES);
    int*   cl1   = (int*)alloc(N_NODES);
    int*   a1    = (int*)alloc(NP0);
    int*   order = (int*)alloc(N_NODES);
    int*   csrt  = (int*)alloc(N_NODES);
    int*   offj  = (int*)alloc(NP0 + 1);
    int*   cursor= (int*)alloc(NP0);
    unsigned long long* amin = (unsigned long long*)alloc((size_t)N_NODES * 2);  // 8B-aligned (256B-aligned allocs)
    // ---- zero-initialized block (single memset) ----
    float* zero0 = ws + off;
    float* bnsum = alloc(64);
    float* bnsq  = alloc(64);
    int*   hist  = (int*)alloc(NP0);
    float* loss1g= alloc(64);
    double* p0d  = (double*)alloc((size_t)NP0 * FEA * 2);   // f64 accumulators
    size_t zbytes = (size_t)((ws + off) - zero0) * sizeof(float);

    float* xb1 = h1b;
    float* xb2 = h2b;
    float* outp = (float*)d_out;

    hipMemsetAsync(zero0, 0, zbytes, stream);
    hipMemsetAsync(amin, 0xFF, (size_t)N_NODES * 8, stream);   // UINT64_MAX for atomicMin

    bn_reduce<<<256, 256, 0, stream>>>(x, bnsum, bnsq);
    bn_apply<<<(N_NODES * FEA) / 256, 256, 0, stream>>>(x, bnsum, bnsq, gamma, beta, x0);

    transpose_W0<<<(FEA * HID + 255) / 256, 256, 0, stream>>>(W0, W0t);
    compute_G2<<<NP0T, 64, 0, stream>>>(W0t, C0, Gt, c0n);
    cnorm<<<NP1, 64, 0, stream>>>(C1, c1n);

    int mtiles = (N_NODES + 127) / 128;            // 391
    argmin0_split<<<mtiles * 4, 256, 0, stream>>>(xcov, Gt, c0n, amin);

    hist0<<<(N_NODES + 255) / 256, 256, 0, stream>>>(amin, a0, hist);
    scan0<<<1, 256, 0, stream>>>(hist, offj, cursor);
    scatter0<<<(N_NODES + 255) / 256, 256, 0, stream>>>(a0, cursor, order, csrt);
    pool0seg<<<(N_NODES + 63) / 64, 256, 0, stream>>>(order, csrt, xcov, p0d);
    pool_fin0<<<(NP0 * FEA + 255) / 256, 256, 0, stream>>>(p0d, hist, p0, NP0 * FEA);

    level1<<<NP0, 64, 0, stream>>>(p0, W1, C1, c1n, a1);
    pool1<<<NP1, 256, 0, stream>>>(p0, a1, p1);

    level2<<<1, 256, 0, stream>>>(p1, fc, corr2, g1sq, loss2f);
    corr1_g0<<<(NP0 + 3) / 4, 256, 0, stream>>>(p0, p1, a1, corr2, g0sq, loss1g);
    loss_final<<<1, 64, 0, stream>>>(loss1g, loss2f, outp + (size_t)N_NODES * NCLS);

    cl1map<<<(N_NODES + 255) / 256, 256, 0, stream>>>(a0, a1, cl1);

    prop<<<N_NODES / 4, 256, 0, stream>>>(x0, x0, cols, avals, a0, cl1, g0sq, g1sq, xb1);
    prop<<<N_NODES / 4, 256, 0, stream>>>(xb1, x0, cols, avals, a0, cl1, g0sq, g1sq, xb2);

    int gemmGrid = mtiles * 2;    // 391 m-tiles x 2 n-tiles
    gemm_prelu<<<gemmGrid, 256, 0, stream>>>(xb2, x0, nullptr, nullptr, 2, FEA,
                                             mW1, mb1, mp1, h1b);
    gemm_prelu<<<gemmGrid, 256, 0, stream>>>(h1b, h1b + 64, h1b + 128, h1b + 192, 4, HID,
                                             mW2, mb2, mp2, h2b);
    mlp3<<<N_NODES / 16, 256, 0, stream>>>(h2b, mW3, mb3, outp);
}

// Round 10
// 704.016 us; speedup vs baseline: 1.1984x; 1.1984x over previous
//
#include <hip/hip_runtime.h>
#include <math.h>

#define N_NODES 50000
#define FEA 64
#define DEG 16
#define HID 256
#define NCLS 16
#define NP0 1351
#define NP0T 1408   // padded to 11*128
#define CTILES 11
#define NP1 37
#define EPSV 1e-5f

// ---------------- BatchNorm ----------------
__global__ __launch_bounds__(256) void bn_reduce(const float* __restrict__ x,
                                                 float* __restrict__ bnsum, float* __restrict__ bnsq) {
    __shared__ float s1[256], s2[256];
    int tid = threadIdx.x;
    int f = tid & 63, sub = tid >> 6;
    float a = 0.f, b = 0.f;
    for (int r = blockIdx.x * 4 + sub; r < N_NODES; r += gridDim.x * 4) {
        float v = x[r * FEA + f];
        a += v; b += v * v;
    }
    s1[tid] = a; s2[tid] = b;
    __syncthreads();
    if (tid < 64) {
        a = s1[tid] + s1[tid + 64] + s1[tid + 128] + s1[tid + 192];
        b = s2[tid] + s2[tid + 64] + s2[tid + 128] + s2[tid + 192];
        atomicAdd(&bnsum[tid], a);
        atomicAdd(&bnsq[tid], b);
    }
}

__global__ __launch_bounds__(256) void bn_apply(const float* __restrict__ x,
                                                const float* __restrict__ bnsum, const float* __restrict__ bnsq,
                                                const float* __restrict__ gamma, const float* __restrict__ beta,
                                                float* __restrict__ x0) {
    int gid = blockIdx.x * 256 + threadIdx.x;
    if (gid >= N_NODES * FEA) return;
    int f = gid & 63;
    float mu = bnsum[f] * (1.0f / N_NODES);
    float var = bnsq[f] * (1.0f / N_NODES) - mu * mu;
    float sc = gamma[f] / sqrtf(var + EPSV);
    x0[gid] = (x[gid] - mu) * sc + beta[f];
}

// ---------------- W0 transpose (64x256 -> 256x64) for coalesced G build ----------------
__global__ void transpose_W0(const float* __restrict__ W0, float* __restrict__ W0t) {
    int idx = blockIdx.x * 256 + threadIdx.x;
    if (idx < FEA * HID) {
        int f = idx >> 8, h = idx & 255;
        W0t[h * FEA + f] = W0[idx];
    }
}

// ---------------- Gt[k][j] = sum_m W0t[m][k]*C0[j][m]; c0n[j]=||C0_j||^2; pad j>=NP0 ----------------
__global__ __launch_bounds__(64) void compute_G2(const float* __restrict__ W0t, const float* __restrict__ C0,
                                                 float* __restrict__ Gt, float* __restrict__ c0n) {
    int j = blockIdx.x, k = threadIdx.x;           // 1408 blocks x 64 threads
    if (j >= NP0) {
        Gt[k * NP0T + j] = 0.f;
        if (k == 0) c0n[j] = 3.4e38f;
        return;
    }
    const float* c = C0 + j * HID;                 // wave-uniform reads
    float acc = 0.f;
    for (int m = 0; m < HID; ++m) acc += W0t[m * FEA + k] * c[m];   // coalesced over k
    Gt[k * NP0T + j] = acc;
    float cn = 0.f;
    for (int m = k; m < HID; m += 64) { float v = c[m]; cn += v * v; }
    for (int off = 32; off; off >>= 1) cn += __shfl_xor(cn, off);
    if (k == 0) c0n[j] = cn;
}

__global__ void cnorm(const float* __restrict__ C, float* __restrict__ cn) {
    int j = blockIdx.x, k = threadIdx.x;           // 37 blocks x 64 threads
    const float* c = C + j * HID;
    float acc = 0.f;
    for (int m = k; m < HID; m += 64) { float v = c[m]; acc += v * v; }
    for (int off = 32; off; off >>= 1) acc += __shfl_xor(acc, off);
    if (k == 0) cn[j] = acc;
}

// ---------------- level-0 argmin: 128x128 tile, 8x8/thread, 4 j-chunks, half-k B staging ----------------
__global__ __launch_bounds__(256, 2) void argmin0_split(const float* __restrict__ xcov,
                                                        const float* __restrict__ Gt,
                                                        const float* __restrict__ c0n,
                                                        unsigned long long* __restrict__ amin) {
    __shared__ float As[64 * 140];   // As[k][fr(r)], fr = r + 4*(r>>5)
    __shared__ float Bs[32 * 132];   // half-k tile: Bs[k2][j]
    __shared__ float cs[128];
    int t = threadIdx.x;
    int row0 = (blockIdx.x >> 2) * 128;
    int chunk = blockIdx.x & 3;
    int tile0 = chunk * 3;
    int tile1 = tile0 + 3; if (tile1 > CTILES) tile1 = CTILES;   // chunk 3: tiles 9,10

    // stage A: 2 threads per row, 32 k-entries each
    {
        int r = t & 127, half = t >> 7;
        int row = row0 + r;
        int fr = r + 4 * (r >> 5);
        if (row < N_NODES) {
            const float4* xp = (const float4*)(xcov + (size_t)row * FEA + half * 32);
            #pragma unroll
            for (int u = 0; u < 8; ++u) {
                float4 v = xp[u];
                int k = half * 32 + u * 4;
                As[(k+0)*140 + fr] = v.x; As[(k+1)*140 + fr] = v.y;
                As[(k+2)*140 + fr] = v.z; As[(k+3)*140 + fr] = v.w;
            }
        } else {
            #pragma unroll
            for (int u = 0; u < 8; ++u) {
                int k = half * 32 + u * 4;
                As[(k+0)*140+fr] = 0.f; As[(k+1)*140+fr] = 0.f;
                As[(k+2)*140+fr] = 0.f; As[(k+3)*140+fr] = 0.f;
            }
        }
    }

    int tr = t & 15, tc = t >> 4;
    int aoff = 8 * tr + 4 * (tr >> 2);   // f(8*tr)
    int boff = 8 * tc;
    int bkk = t >> 3, bpart = t & 7;     // B staging: 32 rows, 8 threads/row, 4 float4 each
    unsigned long long best[8];
    #pragma unroll
    for (int r = 0; r < 8; ++r) best[r] = ~0ull;

    for (int tile = tile0; tile < tile1; ++tile) {
        int j0 = tile * 128;
        float acc[8][8];
        #pragma unroll
        for (int r = 0; r < 8; ++r)
            #pragma unroll
            for (int c = 0; c < 8; ++c) acc[r][c] = 0.f;

        for (int kh = 0; kh < 2; ++kh) {
            __syncthreads();               // Bs/cs safe to overwrite
            {
                const float* gr = Gt + (size_t)(kh * 32 + bkk) * NP0T + j0;
                #pragma unroll
                for (int u = 0; u < 4; ++u) {
                    int gi = bpart + 8 * u;
                    float4 v = *(const float4*)(gr + gi * 4);
                    *(float4*)(Bs + bkk * 132 + gi * 4) = v;
                }
            }
            if (kh == 0 && t < 128) cs[t] = c0n[j0 + t];
            __syncthreads();
            #pragma unroll 4
            for (int k2 = 0; k2 < 32; ++k2) {
                int k = kh * 32 + k2;
                float4 av0 = *(const float4*)(As + k * 140 + aoff);
                float4 av1 = *(const float4*)(As + k * 140 + aoff + 4);
                float4 bv0 = *(const float4*)(Bs + k2 * 132 + boff);
                float4 bv1 = *(const float4*)(Bs + k2 * 132 + boff + 4);
                float av[8] = {av0.x, av0.y, av0.z, av0.w, av1.x, av1.y, av1.z, av1.w};
                float bv[8] = {bv0.x, bv0.y, bv0.z, bv0.w, bv1.x, bv1.y, bv1.z, bv1.w};
                #pragma unroll
                for (int r = 0; r < 8; ++r)
                    #pragma unroll
                    for (int c = 0; c < 8; ++c) acc[r][c] += av[r] * bv[c];
            }
        }
        #pragma unroll
        for (int c = 0; c < 8; ++c) {
            int j = j0 + boff + c;
            float cn = cs[boff + c];
            #pragma unroll
            for (int r = 0; r < 8; ++r) {
                float d = cn - 2.0f * acc[r][c];
                unsigned s = __float_as_uint(d);
                unsigned u2 = ((int)s < 0) ? ~s : (s | 0x80000000u);  // monotone float->uint
                unsigned long long p = ((unsigned long long)u2 << 32) | (unsigned)j;
                if (p < best[r]) best[r] = p;
            }
        }
    }

    __syncthreads();
    unsigned long long* pmin = (unsigned long long*)Bs;   // 128*16*8 = 16384 <= 16896, fits
    #pragma unroll
    for (int r = 0; r < 8; ++r) pmin[(8 * tr + r) * 16 + tc] = best[r];
    __syncthreads();
    if (t < 128) {
        unsigned long long b = pmin[t * 16];
        #pragma unroll
        for (int q = 1; q < 16; ++q) {
            unsigned long long v = pmin[t * 16 + q];
            if (v < b) b = v;
        }
        int row = row0 + t;
        if (row < N_NODES) atomicMin(&amin[row], b);
    }
}

// ---------------- a0 extraction + wave-aggregated histogram ----------------
__global__ __launch_bounds__(256) void hist0(const unsigned long long* __restrict__ amin,
                                             int* __restrict__ a0, int* __restrict__ hist) {
    int i = blockIdx.x * 256 + threadIdx.x;
    bool act = i < N_NODES;
    int j = act ? (int)(unsigned)amin[i] : -1;
    if (act) a0[i] = j;
    unsigned long long todo = __ballot(act);
    int lane = threadIdx.x & 63;
    while (todo) {
        int leader = __ffsll((long long)todo) - 1;
        int lj = __shfl(j, leader);
        unsigned long long grp = __ballot(act && j == lj);
        if (lane == leader) atomicAdd(&hist[lj], __popcll(grp));
        todo &= ~grp;
    }
}

__global__ __launch_bounds__(256) void scan0(const int* __restrict__ hist, int* __restrict__ off,
                                             int* __restrict__ cursor) {
    __shared__ int wsum[4];
    int t = threadIdx.x;
    int c0 = t * 6;                      // 256*6 = 1536 >= 1351
    int loc[6]; int s = 0;
    #pragma unroll
    for (int u = 0; u < 6; ++u) {
        int j = c0 + u;
        int h = (j < NP0) ? hist[j] : 0;
        loc[u] = s; s += h;
    }
    int lane = t & 63, w = t >> 6;
    int v = s;
    #pragma unroll
    for (int d = 1; d < 64; d <<= 1) {
        int up = __shfl_up(v, d);
        if (lane >= d) v += up;
    }
    if (lane == 63) wsum[w] = v;
    __syncthreads();
    int woff = 0;
    for (int q = 0; q < w; ++q) woff += wsum[q];
    int excl = woff + v - s;             // exclusive prefix of this thread's chunk
    #pragma unroll
    for (int u = 0; u < 6; ++u) {
        int j = c0 + u;
        if (j < NP0) { off[j] = excl + loc[u]; cursor[j] = excl + loc[u]; }
    }
    if (t == 255) off[NP0] = excl + s;   // total = N_NODES
}

__global__ __launch_bounds__(256) void scatter0(const int* __restrict__ a0, int* __restrict__ cursor,
                                                int* __restrict__ order, int* __restrict__ csrt) {
    int i = blockIdx.x * 256 + threadIdx.x;
    bool act = i < N_NODES;
    int j = act ? a0[i] : -1;
    int lane = threadIdx.x & 63;
    unsigned long long todo = __ballot(act);
    int pos = 0;
    while (todo) {
        int leader = __ffsll((long long)todo) - 1;
        int lj = __shfl(j, leader);
        unsigned long long grp = __ballot(act && j == lj);
        int base = 0;
        if (lane == leader) base = atomicAdd(&cursor[lj], __popcll(grp));
        base = __shfl(base, leader);
        if (act && j == lj)
            pos = base + __popcll(grp & ((1ull << lane) - 1ull));
        todo &= ~grp;
    }
    if (act) { order[pos] = i; csrt[pos] = j; }
}

// ---------------- skew-robust pooled sum, DOUBLE accumulation (replay-deterministic) ----------------
__global__ __launch_bounds__(256) void pool0seg(const int* __restrict__ order, const int* __restrict__ csrt,
                                                const float* __restrict__ xcov, double* __restrict__ p0d) {
    int lane = threadIdx.x & 63;
    int w = threadIdx.x >> 6;
    int base = (blockIdx.x * 4 + w) * 16;
    if (base >= N_NODES) return;
    int n = N_NODES - base; if (n > 16) n = 16;
    float vals[16]; int cl[16];
    #pragma unroll
    for (int r = 0; r < 16; ++r) {
        if (r < n) {
            int idx = order[base + r];        // wave-uniform -> broadcast
            cl[r] = csrt[base + r];
            vals[r] = xcov[(size_t)idx * FEA + lane];   // coalesced 256B row
        } else { cl[r] = -1; vals[r] = 0.f; }
    }
    double acc = (double)vals[0]; int cur = cl[0];
    #pragma unroll
    for (int r = 1; r < 16; ++r) {
        if (r < n) {
            if (cl[r] == cur) { acc += (double)vals[r]; }
            else { atomicAdd(&p0d[(size_t)cur * FEA + lane], acc); acc = (double)vals[r]; cur = cl[r]; }
        }
    }
    atomicAdd(&p0d[(size_t)cur * FEA + lane], acc);
}

__global__ void pool_fin0(const double* __restrict__ p0d, const int* __restrict__ hist,
                          float* __restrict__ p0, int total) {
    int gid = blockIdx.x * 256 + threadIdx.x;
    if (gid < total) p0[gid] = (float)(p0d[gid] / (double)max(hist[gid >> 6], 1));
}

// ---------------- level-1: h1 = p0 @ W1, argmin vs C1 (a1 only) ----------------
__global__ __launch_bounds__(64) void level1(const float* __restrict__ p0, const float* __restrict__ W1,
                                             const float* __restrict__ C1, const float* __restrict__ c1n,
                                             int* __restrict__ a1) {
    int i = blockIdx.x;          // 1351 blocks, one wave each
    int lane = threadIdx.x;
    const float* pr = p0 + (size_t)i * FEA;
    float h[4] = {0.f, 0.f, 0.f, 0.f};
    for (int k = 0; k < FEA; ++k) {
        float pv = pr[k];                         // wave-uniform
        #pragma unroll
        for (int q = 0; q < 4; ++q) h[q] += pv * W1[k * HID + q * 64 + lane];
    }
    float hh = h[0]*h[0] + h[1]*h[1] + h[2]*h[2] + h[3]*h[3];
    for (int off = 32; off; off >>= 1) hh += __shfl_xor(hh, off);
    float best = 3.4e38f; int bj = 0;
    for (int j = 0; j < NP1; ++j) {
        const float* cj = C1 + j * HID;
        float dp = h[0]*cj[lane] + h[1]*cj[64+lane] + h[2]*cj[128+lane] + h[3]*cj[192+lane];
        for (int off = 32; off; off >>= 1) dp += __shfl_xor(dp, off);
        float d = hh - 2.0f * dp + c1n[j];
        if (d < best) { best = d; bj = j; }
    }
    if (lane == 0) a1[i] = bj;
}

// ---------------- pool p0 -> p1: latency-hiding rewrite ----------------
// Old version: 37 blocks x 4 waves, each wave serially scanning 1351 global a1 entries with
// branch-then-load => ~130 us of raw latency (VALUBusy 0.25%). New: stage a1 in LDS, per-wave
// ballot stream-compaction into a match list, then 4-batched row loads (independent, pipelined).
// Summation order fixed (ascending i per wave, fixed wave order) => deterministic across replays.
#define P1W 16
__global__ __launch_bounds__(1024) void pool1(const float* __restrict__ p0, const int* __restrict__ a1,
                                              float* __restrict__ p1) {
    __shared__ int a1s[NP0];
    __shared__ int lists[NP0 + P1W];   // per-wave segment starts at w*per
    __shared__ float psum[P1W][64];
    __shared__ int pcnt[P1W];
    int j = blockIdx.x;                // 37 blocks
    int t = threadIdx.x;
    int lane = t & 63, w = t >> 6;
    for (int i = t; i < NP0; i += 1024) a1s[i] = a1[i];
    __syncthreads();
    const int per = (NP0 + P1W - 1) / P1W;    // 85
    int s0 = w * per;
    int s1 = s0 + per; if (s1 > NP0) s1 = NP0;
    int cnt = 0;
    for (int base = s0; base < s1; base += 64) {
        int i = base + lane;
        bool m = (i < s1) && (a1s[i] == j);
        unsigned long long mask = __ballot(m);
        int rank = __popcll(mask & ((1ull << lane) - 1ull));
        if (m) lists[s0 + cnt + rank] = i;
        cnt += __popcll(mask);
    }
    float acc = 0.f;
    int m4 = cnt & ~3;
    for (int m = 0; m < m4; m += 4) {
        int i0 = lists[s0 + m], i1 = lists[s0 + m + 1], i2 = lists[s0 + m + 2], i3 = lists[s0 + m + 3];
        float v0 = p0[i0 * FEA + lane];
        float v1 = p0[i1 * FEA + lane];
        float v2 = p0[i2 * FEA + lane];
        float v3 = p0[i3 * FEA + lane];
        acc += ((v0 + v1) + (v2 + v3));
    }
    for (int m = m4; m < cnt; ++m) acc += p0[lists[s0 + m] * FEA + lane];
    psum[w][lane] = acc;
    if (lane == 0) pcnt[w] = cnt;
    __syncthreads();
    if (w == 0) {
        float s = 0.f; int c = 0;
        #pragma unroll
        for (int q = 0; q < P1W; ++q) { s += psum[q][lane]; c += pcnt[q]; }
        p1[j * FEA + lane] = s / fmaxf((float)c, 1.0f);
    }
}

// ---------------- level-2 (N2=1 => a2==0): p2 = mean(p1), corr2, g1sq, loss part 2 ----------------
__global__ __launch_bounds__(256) void level2(const float* __restrict__ p1, const float* __restrict__ fc,
                                              float* __restrict__ corr2, float* __restrict__ g1sq,
                                              float* __restrict__ loss2f) {
    __shared__ float p2s[64];
    __shared__ float lacc[64];
    int tid = threadIdx.x;
    if (tid < 64) {
        float s = 0.f;
        for (int i = 0; i < NP1; ++i) s += p1[i * FEA + tid];
        p2s[tid] = s * (1.0f / NP1);
        lacc[tid] = 0.f;
    }
    __syncthreads();
    for (int t = tid; t < NP1 * FEA; t += 256) {
        int f = t & 63;
        float dv = p1[t] - p2s[f];
        float c2 = dv * dv;
        corr2[t] = c2;
        float sg = 2.0f / (1.0f + __expf(-(fc[f] - c2)));
        g1sq[t] = sg * sg;
        atomicAdd(&lacc[f], c2);
    }
    __syncthreads();
    if (tid < 64) loss2f[tid] = lacc[tid] * (1.0f / NP1);
}

// ---------------- corr1, g0sq, loss part 1 ----------------
__global__ __launch_bounds__(256) void corr1_g0(const float* __restrict__ p0, const float* __restrict__ p1,
                                                const int* __restrict__ a1, const float* __restrict__ corr2,
                                                float* __restrict__ g0sq, float* __restrict__ loss1g) {
    __shared__ float sh[256];
    int tid = threadIdx.x;
    int f = tid & 63, sub = tid >> 6;
    int i = blockIdx.x * 4 + sub;
    float c1v = 0.f;
    if (i < NP0) {
        int a = a1[i];
        float dv = p0[i * FEA + f] - p1[a * FEA + f];
        c1v = dv * dv;
        float sg = 2.0f / (1.0f + __expf(-(corr2[a * FEA + f] - c1v)));
        g0sq[i * FEA + f] = sg * sg;
    }
    sh[tid] = c1v;
    __syncthreads();
    if (tid < 64) atomicAdd(&loss1g[tid], sh[tid] + sh[tid+64] + sh[tid+128] + sh[tid+192]);
}

__global__ void loss_final(const float* __restrict__ loss1g, const float* __restrict__ loss2f,
                           float* __restrict__ out_loss) {
    int lane = threadIdx.x;
    float v = loss1g[lane] * (1.0f / NP0) + loss2f[lane];
    for (int off = 32; off; off >>= 1) v += __shfl_xor(v, off);
    if (lane == 0) out_loss[0] = v * (1.0f / FEA) * 0.5f;   // /(NPOOL-1)
}

__global__ void cl1map(const int* __restrict__ a0, const int* __restrict__ a1, int* __restrict__ cl1) {
    int i = blockIdx.x * 256 + threadIdx.x;
    if (i < N_NODES) cl1[i] = a1[a0[i]];
}

// ---------------- fused per-row softmax + propagation, one wave per row ----------------
__global__ __launch_bounds__(256) void prop(const float* __restrict__ xin, const float* __restrict__ x0,
                                            const int* __restrict__ cols, const float* __restrict__ avals,
                                            const int* __restrict__ cl0, const int* __restrict__ cl1,
                                            const float* __restrict__ g0sq, const float* __restrict__ g1sq,
                                            float* __restrict__ xout) {
    int lane = threadIdx.x & 63;
    int i = blockIdx.x * 4 + __builtin_amdgcn_readfirstlane(threadIdx.x >> 6);
    int s0 = cl0[i], s1 = cl1[i];
    float g0f = g0sq[s0 * FEA + lane];
    float g1f = g1sq[s1 * FEA + lane];
    float x0f = x0[(size_t)i * FEA + lane];
    int ce[DEG]; float v[DEG];
    float m = -3.4e38f;
    #pragma unroll
    for (int e = 0; e < DEG; ++e) {
        int c = cols[i * DEG + e];
        ce[e] = c;
        float val = avals[i * DEG + e];
        if (cl0[c] == s0) val += g0f;
        if (cl1[c] == s1) val += g1f;
        v[e] = val;
        m = fmaxf(m, val);
    }
    float se = 0.f, acc = 0.f;
    #pragma unroll
    for (int e = 0; e < DEG; ++e) {
        float w = __expf(v[e] - m);
        se += w;
        acc += w * xin[(size_t)ce[e] * FEA + lane];
    }
    xout[(size_t)i * FEA + lane] = acc / se + x0f;   // ALPHA = 1
}

// ---------------- fused GEMM + bias + PReLU: C[M x 128-tile] = A(chunked K) @ W + b ----------------
__global__ __launch_bounds__(256, 2) void gemm_prelu(const float* __restrict__ s0, const float* __restrict__ s1,
                                                     const float* __restrict__ s2, const float* __restrict__ s3,
                                                     int nchunks, int lda,
                                                     const float* __restrict__ W, const float* __restrict__ b,
                                                     const float* __restrict__ pp, float* __restrict__ out) {
    __shared__ float As[64 * 144];   // As[k][fr(r)], fr = r + 4*(r>>5)
    __shared__ float Bs[64 * 140];   // Bs[k][fc(n)], fc = n + 4*(n>>5)
    int t = threadIdx.x;
    int mt = blockIdx.x >> 1, nt = blockIdx.x & 1;
    int row0 = mt * 128, n0 = nt * 128;
    int tr = t & 15, tc = t >> 4;
    int aoff = 8 * tr + 4 * (tr >> 2);
    int boff = 8 * tc + 4 * (tc >> 2);

    float acc[8][8];
    #pragma unroll
    for (int r = 0; r < 8; ++r)
        #pragma unroll
        for (int c = 0; c < 8; ++c) acc[r][c] = 0.f;

    int ar = t & 127, ahalf = t >> 7;      // A staging: 2 threads/row, 32 k each
    int arow = row0 + ar;
    int afr = ar + 4 * (ar >> 5);
    int bkk = t >> 2, bpart = t & 3;       // B staging: thread per k-row quarter

    for (int c = 0; c < nchunks; ++c) {
        const float* Ap = (c == 0) ? s0 : (c == 1) ? s1 : (c == 2) ? s2 : s3;
        __syncthreads();
        // stage A chunk (transposed)
        if (arow < N_NODES) {
            const float4* xp = (const float4*)(Ap + (size_t)arow * lda + ahalf * 32);
            #pragma unroll
            for (int u = 0; u < 8; ++u) {
                float4 v = xp[u];
                int k = ahalf * 32 + u * 4;
                As[(k+0)*144 + afr] = v.x; As[(k+1)*144 + afr] = v.y;
                As[(k+2)*144 + afr] = v.z; As[(k+3)*144 + afr] = v.w;
            }
        } else {
            #pragma unroll
            for (int u = 0; u < 8; ++u) {
                int k = ahalf * 32 + u * 4;
                As[(k+0)*144+afr] = 0.f; As[(k+1)*144+afr] = 0.f;
                As[(k+2)*144+afr] = 0.f; As[(k+3)*144+afr] = 0.f;
            }
        }
        // stage B chunk: W rows c*64+kk, cols n0..n0+127
        {
            const float* wr = W + (size_t)(c * 64 + bkk) * HID + n0;
            #pragma unroll
            for (int u = 0; u < 8; ++u) {
                int ci = (bpart + 4 * u) * 4;            // 0..124 step 4
                float4 v = *(const float4*)(wr + ci);
                int fc = ci + 4 * (ci >> 5);
                *(float4*)(Bs + bkk * 140 + fc) = v;
            }
        }
        __syncthreads();
        for (int k = 0; k < 64; ++k) {
            float4 av0 = *(const float4*)(As + k * 144 + aoff);
            float4 av1 = *(const float4*)(As + k * 144 + aoff + 4);
            float4 bv0 = *(const float4*)(Bs + k * 140 + boff);
            float4 bv1 = *(const float4*)(Bs + k * 140 + boff + 4);
            float av[8] = {av0.x, av0.y, av0.z, av0.w, av1.x, av1.y, av1.z, av1.w};
            float bv[8] = {bv0.x, bv0.y, bv0.z, bv0.w, bv1.x, bv1.y, bv1.z, bv1.w};
            #pragma unroll
            for (int r = 0; r < 8; ++r)
                #pragma unroll
                for (int cc = 0; cc < 8; ++cc) acc[r][cc] += av[r] * bv[cc];
        }
    }
    // epilogue: bias + PReLU, cols n0+8*tc .. +7 (contiguous)
    float p = pp[0];
    float bb[8];
    #pragma unroll
    for (int cc = 0; cc < 8; ++cc) bb[cc] = b[n0 + 8 * tc + cc];
    #pragma unroll
    for (int r = 0; r < 8; ++r) {
        int row = row0 + 8 * tr + r;
        if (row >= N_NODES) break;
        float* o = out + (size_t)row * HID + n0 + 8 * tc;
        float4 o0, o1;
        float h;
        h = acc[r][0] + bb[0]; o0.x = h >= 0.f ? h : p * h;
        h = acc[r][1] + bb[1]; o0.y = h >= 0.f ? h : p * h;
        h = acc[r][2] + bb[2]; o0.z = h >= 0.f ? h : p * h;
        h = acc[r][3] + bb[3]; o0.w = h >= 0.f ? h : p * h;
        h = acc[r][4] + bb[4]; o1.x = h >= 0.f ? h : p * h;
        h = acc[r][5] + bb[5]; o1.y = h >= 0.f ? h : p * h;
        h = acc[r][6] + bb[6]; o1.z = h >= 0.f ? h : p * h;
        h = acc[r][7] + bb[7]; o1.w = h >= 0.f ? h : p * h;
        *(float4*)(o) = o0;
        *(float4*)(o + 4) = o1;
    }
}

// ---------------- MLP layer 3 + log_softmax; lane = (row_sub, class) ----------------
__global__ __launch_bounds__(256) void mlp3(const float* __restrict__ hin, const float* __restrict__ W3,
                                            const float* __restrict__ b3, float* __restrict__ out) {
    __shared__ float Ws[HID * NCLS];
    int tid = threadIdx.x;
    for (int t = tid; t < HID * NCLS; t += 256) Ws[t] = W3[t];
    __syncthreads();
    int lane = tid & 63;
    int wv = __builtin_amdgcn_readfirstlane(tid >> 6);
    int rs = lane >> 4, c = lane & 15;
    int row = blockIdx.x * 16 + wv * 4 + rs;    // 3125 blocks * 16 rows = 50000 exactly
    const float4* hr = (const float4*)(hin + (size_t)row * HID);
    float acc = b3[c];
    for (int k4 = 0; k4 < 64; ++k4) {
        float4 h = hr[k4];
        int k = k4 * 4;
        acc += h.x * Ws[k * NCLS + c];
        acc += h.y * Ws[(k + 1) * NCLS + c];
        acc += h.z * Ws[(k + 2) * NCLS + c];
        acc += h.w * Ws[(k + 3) * NCLS + c];
    }
    float m = acc;
    #pragma unroll
    for (int off = 1; off < 16; off <<= 1) m = fmaxf(m, __shfl_xor(m, off));
    float e = __expf(acc - m);
    float s = e;
    #pragma unroll
    for (int off = 1; off < 16; off <<= 1) s += __shfl_xor(s, off);
    out[(size_t)row * NCLS + c] = acc - m - __logf(s);
}

extern "C" void kernel_launch(void* const* d_in, const int* in_sizes, int n_in,
                              void* d_out, int out_size, void* d_ws, size_t ws_size,
                              hipStream_t stream) {
    const float* x     = (const float*)d_in[0];
    const float* xcov  = (const float*)d_in[1];
    const float* avals = (const float*)d_in[2];
    const float* fc    = (const float*)d_in[3];
    const float* gamma = (const float*)d_in[4];
    const float* beta  = (const float*)d_in[5];
    const float* W0    = (const float*)d_in[6];
    const float* C0    = (const float*)d_in[7];
    const float* W1    = (const float*)d_in[8];
    const float* C1    = (const float*)d_in[9];
    // d_in[10], d_in[11] (W2, C2) only affect a2, which is argmin over 1 cluster -> always 0. Unused.
    const float* mW1   = (const float*)d_in[12];
    const float* mb1   = (const float*)d_in[13];
    const float* mp1   = (const float*)d_in[14];
    const float* mW2   = (const float*)d_in[15];
    const float* mb2   = (const float*)d_in[16];
    const float* mp2   = (const float*)d_in[17];
    const float* mW3   = (const float*)d_in[18];
    const float* mb3   = (const float*)d_in[19];
    // d_in[20] adj_rows == repeat(arange(N), 16) -> row of edge e is e>>4. Unused.
    const int* cols    = (const int*)d_in[21];

    float* ws = (float*)d_ws;
    size_t off = 0;
    auto alloc = [&](size_t n) { float* p = ws + off; off += (n + 63) & ~(size_t)63; return p; };

    float* x0    = alloc((size_t)N_NODES * FEA);
    float* h1b   = alloc((size_t)N_NODES * HID);   // xb1 aliases its head
    float* h2b   = alloc((size_t)N_NODES * HID);   // xb2 aliases its head
    float* W0t   = alloc(HID * FEA);
    float* Gt    = alloc((size_t)FEA * NP0T);
    float* c0n   = alloc(NP0T);
    float* c1n   = alloc(NP1);
    float* g0sq  = alloc(NP0 * FEA);
    float* g1sq  = alloc(NP1 * FEA);
    float* corr2 = alloc(NP1 * FEA);
    float* loss2f= alloc(64);
    float* p1    = alloc(NP1 * FEA);
    float* p0    = alloc(NP0 * FEA);               // written by pool_fin0
    int*   a0    = (int*)alloc(N_NODES);
    int*   cl1   = (int*)alloc(N_NODES);
    int*   a1    = (int*)alloc(NP0);
    int*   order = (int*)alloc(N_NODES);
    int*   csrt  = (int*)alloc(N_NODES);
    int*   offj  = (int*)alloc(NP0 + 1);
    int*   cursor= (int*)alloc(NP0);
    unsigned long long* amin = (unsigned long long*)alloc((size_t)N_NODES * 2);  // 8B-aligned (256B-aligned allocs)
    // ---- zero-initialized block (single memset) ----
    float* zero0 = ws + off;
    float* bnsum = alloc(64);
    float* bnsq  = alloc(64);
    int*   hist  = (int*)alloc(NP0);
    float* loss1g= alloc(64);
    double* p0d  = (double*)alloc((size_t)NP0 * FEA * 2);   // f64 accumulators
    size_t zbytes = (size_t)((ws + off) - zero0) * sizeof(float);

    float* xb1 = h1b;
    float* xb2 = h2b;
    float* outp = (float*)d_out;

    hipMemsetAsync(zero0, 0, zbytes, stream);
    hipMemsetAsync(amin, 0xFF, (size_t)N_NODES * 8, stream);   // UINT64_MAX for atomicMin

    bn_reduce<<<256, 256, 0, stream>>>(x, bnsum, bnsq);
    bn_apply<<<(N_NODES * FEA) / 256, 256, 0, stream>>>(x, bnsum, bnsq, gamma, beta, x0);

    transpose_W0<<<(FEA * HID + 255) / 256, 256, 0, stream>>>(W0, W0t);
    compute_G2<<<NP0T, 64, 0, stream>>>(W0t, C0, Gt, c0n);
    cnorm<<<NP1, 64, 0, stream>>>(C1, c1n);

    int mtiles = (N_NODES + 127) / 128;            // 391
    argmin0_split<<<mtiles * 4, 256, 0, stream>>>(xcov, Gt, c0n, amin);

    hist0<<<(N_NODES + 255) / 256, 256, 0, stream>>>(amin, a0, hist);
    scan0<<<1, 256, 0, stream>>>(hist, offj, cursor);
    scatter0<<<(N_NODES + 255) / 256, 256, 0, stream>>>(a0, cursor, order, csrt);
    pool0seg<<<(N_NODES + 63) / 64, 256, 0, stream>>>(order, csrt, xcov, p0d);
    pool_fin0<<<(NP0 * FEA + 255) / 256, 256, 0, stream>>>(p0d, hist, p0, NP0 * FEA);

    level1<<<NP0, 64, 0, stream>>>(p0, W1, C1, c1n, a1);
    pool1<<<NP1, 1024, 0, stream>>>(p0, a1, p1);

    level2<<<1, 256, 0, stream>>>(p1, fc, corr2, g1sq, loss2f);
    corr1_g0<<<(NP0 + 3) / 4, 256, 0, stream>>>(p0, p1, a1, corr2, g0sq, loss1g);
    loss_final<<<1, 64, 0, stream>>>(loss1g, loss2f, outp + (size_t)N_NODES * NCLS);

    cl1map<<<(N_NODES + 255) / 256, 256, 0, stream>>>(a0, a1, cl1);

    prop<<<N_NODES / 4, 256, 0, stream>>>(x0, x0, cols, avals, a0, cl1, g0sq, g1sq, xb1);
    prop<<<N_NODES / 4, 256, 0, stream>>>(xb1, x0, cols, avals, a0, cl1, g0sq, g1sq, xb2);

    int gemmGrid = mtiles * 2;    // 391 m-tiles x 2 n-tiles
    gemm_prelu<<<gemmGrid, 256, 0, stream>>>(xb2, x0, nullptr, nullptr, 2, FEA,
                                             mW1, mb1, mp1, h1b);
    gemm_prelu<<<gemmGrid, 256, 0, stream>>>(h1b, h1b + 64, h1b + 128, h1b + 192, 4, HID,
                                             mW2, mb2, mp2, h2b);
    mlp3<<<N_NODES / 16, 256, 0, stream>>>(h2b, mW3, mb3, outp);
}